// Round 4
// baseline (188.240 us; speedup 1.0000x reference)
//
#include <hip/hip_runtime.h>
#include <hip/hip_bf16.h>

typedef __attribute__((ext_vector_type(8))) short short8;
typedef __attribute__((ext_vector_type(4))) short short4v;
typedef __attribute__((ext_vector_type(4))) float floatx4;
typedef unsigned int u32;

#define BB 8
#define CC 256
#define ICH 128
#define TT 4096
#define SS 2048
static constexpr float BN_EPS = 1e-5f;
static constexpr float INV_S  = 1.0f / 2048.0f;
static constexpr float INV_BT = 1.0f / 32768.0f;   // 1/(B*T)

// async global->LDS DMA, 16 B per lane; LDS dest = wave-uniform base + lane*16
typedef const __attribute__((address_space(1))) u32* gas_ptr;
typedef __attribute__((address_space(3))) u32* las_ptr;
__device__ __forceinline__ void gl_lds16(const void* g, void* l) {
    __builtin_amdgcn_global_load_lds((gas_ptr)g, (las_ptr)l, 16, 0, 0);
}

// ---------------------------------------------------------------------------
// XCD ownership model (validated by kpq round-2/3): XCD = blockIdx.x % 8.
// Batch b is pinned to XCD b through the WHOLE pipeline so per-batch
// intermediates (xt[b] 2MB, phi_g[b] 1MB, Mpart[b] 0.5MB, P[b] 128KB,
// wy[b] 2MB) stay resident in that XCD's 4MB L2 across kernel boundaries.
// ---------------------------------------------------------------------------

// ---------------------------------------------------------------------------
// k0x: transpose + convert  x[b][c][t] (f32) -> xt[b][t][c] (bf16).
// flat grid 2112: id<2048 -> b=id&7 (XCD-pinned), ids 2048..2111 convert
// phi_w|g_w -> bf16 Wf.  block 256
// ---------------------------------------------------------------------------
__global__ __launch_bounds__(256) void k0x_transpose(
    const float* __restrict__ x, __hip_bfloat16* __restrict__ xt,
    const float* __restrict__ phi_w, const float* __restrict__ g_w,
    __hip_bfloat16* __restrict__ Wf)
{
    const int id = blockIdx.x;
    if (id >= 2048) {                      // fused weight conversion (64 blocks)
        int idx = (id - 2048) * 256 + threadIdx.x;   // 0..16383, 4 floats each
        const float* src = (idx < 8192) ? (phi_w + (size_t)idx * 4)
                                        : (g_w + (size_t)(idx - 8192) * 4);
        float4 v = *(const float4*)src;
        alignas(8) __hip_bfloat16 t[4];
        t[0] = __float2bfloat16(v.x); t[1] = __float2bfloat16(v.y);
        t[2] = __float2bfloat16(v.z); t[3] = __float2bfloat16(v.w);
        *(short4v*)(Wf + (size_t)idx * 4) = *(const short4v*)t;
        return;
    }

    __shared__ float Tl[64][65];
    const int b = id & 7, rest = id >> 3;            // XCD = b
    const int cb = (rest & 3) * 64, tb = (rest >> 2) * 64;
    const int tid = threadIdx.x;
    #pragma unroll
    for (int it = 0; it < 4; ++it) {
        int idx = tid + 256 * it;
        int row = idx >> 4, c4 = idx & 15;
        float4 v = *(const float4*)(x + ((size_t)b * CC + cb + row) * TT + tb + c4 * 4);
        Tl[row][c4 * 4 + 0] = v.x; Tl[row][c4 * 4 + 1] = v.y;
        Tl[row][c4 * 4 + 2] = v.z; Tl[row][c4 * 4 + 3] = v.w;
    }
    __syncthreads();
    #pragma unroll
    for (int it = 0; it < 2; ++it) {
        int idx = tid + 256 * it;
        int trow = idx >> 3, ch = idx & 7;
        alignas(16) __hip_bfloat16 tmp[8];
        #pragma unroll
        for (int e = 0; e < 8; ++e) tmp[e] = __float2bfloat16(Tl[ch * 8 + e][trow]);
        *(short8*)(xt + ((size_t)b * TT + tb + trow) * CC + cb + ch * 8) = *(const short8*)tmp;
    }
}

// ---------------------------------------------------------------------------
// k1: m97-style MFMA conv1x1 (stacked phi|g) + maxpool2 epilogue.
// flat grid 512: id = b + 8*(m + 2*t) -> XCD = b; both m-blocks of a t-tile
// share the XCD (xt tile fetched once), xt[b] L2-hot from k0x.  block 256.
// ---------------------------------------------------------------------------
__global__ __launch_bounds__(256) void k1_mfma(
    const __hip_bfloat16* __restrict__ Wf, const float* __restrict__ phi_b,
    const float* __restrict__ g_b, const __hip_bfloat16* __restrict__ xt,
    __hip_bfloat16* __restrict__ phi_g)
{
    __shared__ short lds[128 * 132];      // staging (32 KB) / Out (33 KB), reused
    short* As = lds;
    short* Bs = lds + 128 * 64;

    const int id = blockIdx.x;
    const int b  = id & 7;                           // XCD = b
    const int m0 = ((id >> 3) & 1) * 128;
    const int tb = (id >> 4) * 128;       // pre-pool t base
    const int s0 = (id >> 4) * 64;        // pooled output base
    const int tid = threadIdx.x;
    const int w = tid >> 6, l = tid & 63;
    const int quad = l >> 4, lm = l & 15;
    const int wm = (w & 1) * 64, wn = (w >> 1) * 64;
    const int rs = l >> 3, cs = (l & 7) * 8;   // staging row-sub / col

    const __hip_bfloat16* Ap = Wf + (size_t)m0 * CC;
    const __hip_bfloat16* Bp = xt + ((size_t)b * TT + tb) * CC;

    floatx4 acc[4][4];
    #pragma unroll
    for (int i = 0; i < 4; ++i)
        #pragma unroll
        for (int j = 0; j < 4; ++j) acc[i][j] = (floatx4)0.f;

    for (int kc = 0; kc < 4; ++kc) {
        const int k0 = kc * 64;
        const int rbase = w * 32;
        #pragma unroll
        for (int t = 0; t < 4; ++t) {
            gl_lds16(Ap + (size_t)(rbase + t * 8 + rs) * CC + k0 + cs, &As[(rbase + t * 8) * 64]);
            gl_lds16(Bp + (size_t)(rbase + t * 8 + rs) * CC + k0 + cs, &Bs[(rbase + t * 8) * 64]);
        }
        __syncthreads();
        #pragma unroll
        for (int ks = 0; ks < 2; ++ks) {
            short8 a[4], bb[4];
            #pragma unroll
            for (int i = 0; i < 4; ++i)
                a[i] = *(const short8*)&As[(wm + i * 16 + lm) * 64 + ks * 32 + quad * 8];
            #pragma unroll
            for (int j = 0; j < 4; ++j)
                bb[j] = *(const short8*)&Bs[(wn + j * 16 + lm) * 64 + ks * 32 + quad * 8];
            #pragma unroll
            for (int i = 0; i < 4; ++i)
                #pragma unroll
                for (int j = 0; j < 4; ++j)
                    acc[i][j] = __builtin_amdgcn_mfma_f32_16x16x32_bf16(a[i], bb[j], acc[i][j], 0, 0, 0);
        }
        __syncthreads();
    }

    // epilogue: stage pre-pool bf16 tile (stride 132), then pool + bias, wide stores
    __hip_bfloat16* Out = (__hip_bfloat16*)lds;
    #pragma unroll
    for (int i = 0; i < 4; ++i)
        #pragma unroll
        for (int j = 0; j < 4; ++j)
            #pragma unroll
            for (int r = 0; r < 4; ++r)
                Out[(wm + i * 16 + quad * 4 + r) * 132 + wn + j * 16 + lm] =
                    __float2bfloat16(acc[i][j][r]);
    __syncthreads();
    #pragma unroll
    for (int it = 0; it < 4; ++it) {
        int idx = tid + 256 * it;
        int orow = idx >> 3, grp = idx & 7;
        int o = m0 + orow;
        float bias = (o < ICH) ? phi_b[o] : g_b[o - ICH];
        short8 v0 = *(const short8*)&Out[orow * 132 + grp * 16];
        short8 v1 = *(const short8*)&Out[orow * 132 + grp * 16 + 8];
        const __hip_bfloat16* p0 = (const __hip_bfloat16*)&v0;
        const __hip_bfloat16* p1 = (const __hip_bfloat16*)&v1;
        alignas(16) __hip_bfloat16 o8[8];
        #pragma unroll
        for (int e = 0; e < 4; ++e)
            o8[e] = __float2bfloat16(
                fmaxf(__bfloat162float(p0[2 * e]), __bfloat162float(p0[2 * e + 1])) + bias);
        #pragma unroll
        for (int e = 0; e < 4; ++e)
            o8[4 + e] = __float2bfloat16(
                fmaxf(__bfloat162float(p1[2 * e]), __bfloat162float(p1[2 * e + 1])) + bias);
        *(short8*)(phi_g + ((size_t)b * CC + o) * SS + s0 + grp * 8) = *(const short8*)o8;
    }
}

// ---------------------------------------------------------------------------
// k2: MFMA Gram partials over 256-wide s-chunks (phi_g read exactly once):
//   Mpart[b][sc][c'][c] = sum_{s in chunk sc} phi[c'][s] * g[c][s]
// grid (8 b, 8 sc) = 64 blocks, b on the FAST axis -> XCD = b (phi_g[b]
// L2-hot from k1; Mpart[b] stays for kpq).  block 256.
// ---------------------------------------------------------------------------
__global__ __launch_bounds__(256) void k2_mfma(
    const __hip_bfloat16* __restrict__ phi_g, float* __restrict__ Mpart)
{
    __shared__ short lds[2 * 128 * 64];
    short* As = lds;
    short* Bs = lds + 128 * 64;
    const int b = blockIdx.x, sc = blockIdx.y;     // b fast -> XCD = b
    const int tid = threadIdx.x;
    const int w = tid >> 6, l = tid & 63;
    const int quad = l >> 4, lm = l & 15;
    const int wm = (w & 1) * 64, wn = (w >> 1) * 64;
    const int rs = l >> 3, cs = (l & 7) * 8;

    const __hip_bfloat16* Ap = phi_g + (size_t)b * CC * SS + sc * 256;   // phi rows
    const __hip_bfloat16* Bp = Ap + (size_t)ICH * SS;                     // g rows

    floatx4 acc[4][4];
    #pragma unroll
    for (int i = 0; i < 4; ++i)
        #pragma unroll
        for (int j = 0; j < 4; ++j) acc[i][j] = (floatx4)0.f;

    for (int kc = 0; kc < 4; ++kc) {
        const int k0 = kc * 64;
        const int rbase = w * 32;
        #pragma unroll
        for (int t = 0; t < 4; ++t) {
            gl_lds16(Ap + (size_t)(rbase + t * 8 + rs) * SS + k0 + cs, &As[(rbase + t * 8) * 64]);
            gl_lds16(Bp + (size_t)(rbase + t * 8 + rs) * SS + k0 + cs, &Bs[(rbase + t * 8) * 64]);
        }
        __syncthreads();
        #pragma unroll
        for (int ks = 0; ks < 2; ++ks) {
            short8 a[4], bb[4];
            #pragma unroll
            for (int i = 0; i < 4; ++i)
                a[i] = *(const short8*)&As[(wm + i * 16 + lm) * 64 + ks * 32 + quad * 8];
            #pragma unroll
            for (int j = 0; j < 4; ++j)
                bb[j] = *(const short8*)&Bs[(wn + j * 16 + lm) * 64 + ks * 32 + quad * 8];
            #pragma unroll
            for (int i = 0; i < 4; ++i)
                #pragma unroll
                for (int j = 0; j < 4; ++j)
                    acc[i][j] = __builtin_amdgcn_mfma_f32_16x16x32_bf16(a[i], bb[j], acc[i][j], 0, 0, 0);
        }
        __syncthreads();
    }

    float* dst = Mpart + ((size_t)(b * 8 + sc)) * ICH * ICH;
    #pragma unroll
    for (int i = 0; i < 4; ++i)
        #pragma unroll
        for (int j = 0; j < 4; ++j)
            #pragma unroll
            for (int r = 0; r < 4; ++r)
                dst[(size_t)(wm + i * 16 + quad * 4 + r) * ICH + wn + j * 16 + lm] = acc[i][j][r];
}

// ---------------------------------------------------------------------------
// kpq: fused k3a+k3b.  1-D grid of 128, b = bid & 7 so all 16 blocks of a
// batch run on the XCD that produced Mpart[b] (L2-hot 8-way partial sum).
// Each block recomputes its own Kb tile (64 co x 128 c') from w_w and summed
// Mpart (registers -> LDS), then P = Kb @ theta_w (bf16) + q.
// ---------------------------------------------------------------------------
__global__ __launch_bounds__(256) void kpq(
    const float* __restrict__ w_w, const float* __restrict__ Mpart,
    const float* __restrict__ theta_w, const float* __restrict__ theta_b,
    const float* __restrict__ w_b, __hip_bfloat16* __restrict__ P,
    float* __restrict__ q)
{
    __shared__ __align__(16) float ldsf[128 * 68 + 64 * 68];   // 52.2 KB
    const int bid = blockIdx.x;
    const int b    = bid & 7;              // XCD-pinned to Mpart[b]'s producer
    const int rest = bid >> 3;             // 0..15
    const int cob  = (rest >> 2) * 64;
    const int cib  = (rest & 3) * 64;
    const int tid = threadIdx.x;
    const int tx = tid & 15, ty = tid >> 4;

    // ---- stage 1: Kb tile (128 c' x 64 co) in registers ----
    float accK[2][4][4] = {};
    {
        float (*Al)[65] = (float (*)[65])ldsf;
        float (*Bl)[65] = Al + 64;
        for (int cpb2 = 0; cpb2 < 2; ++cpb2) {
            const int cpb = cpb2 * 64;
            for (int kc2 = 0; kc2 < 2; ++kc2) {
                #pragma unroll
                for (int r = 0; r < 4; ++r) {
                    int idx = tid + 256 * r;
                    int row = idx >> 4, c4 = idx & 15;
                    float4 v = *(const float4*)(w_w + (size_t)(cob + row) * ICH + kc2 * 64 + c4 * 4);
                    Al[c4 * 4 + 0][row] = v.x; Al[c4 * 4 + 1][row] = v.y;
                    Al[c4 * 4 + 2][row] = v.z; Al[c4 * 4 + 3][row] = v.w;
                    float4 s = {0.f, 0.f, 0.f, 0.f};
                    #pragma unroll
                    for (int sc = 0; sc < 8; ++sc) {
                        float4 m = *(const float4*)(Mpart + (((size_t)b * 8 + sc) * ICH + cpb + row) * ICH + kc2 * 64 + c4 * 4);
                        s.x += m.x; s.y += m.y; s.z += m.z; s.w += m.w;
                    }
                    Bl[c4 * 4 + 0][row] = s.x; Bl[c4 * 4 + 1][row] = s.y;
                    Bl[c4 * 4 + 2][row] = s.z; Bl[c4 * 4 + 3][row] = s.w;
                }
                __syncthreads();
                for (int k = 0; k < 64; ++k) {
                    float av[4], bv[4];
                    #pragma unroll
                    for (int i = 0; i < 4; ++i) av[i] = Al[k][ty + 16 * i];
                    #pragma unroll
                    for (int j = 0; j < 4; ++j) bv[j] = Bl[k][tx + 16 * j];
                    #pragma unroll
                    for (int i = 0; i < 4; ++i)
                        #pragma unroll
                        for (int j = 0; j < 4; ++j) accK[cpb2][i][j] += av[i] * bv[j];
                }
                __syncthreads();
            }
        }
    }

    // ---- publish Kb tile to LDS: KbL[c'][co] ----
    float (*KbL)[68] = (float (*)[68])ldsf;                 // [128][68]
    #pragma unroll
    for (int cpb2 = 0; cpb2 < 2; ++cpb2)
        #pragma unroll
        for (int i = 0; i < 4; ++i)
            #pragma unroll
            for (int j = 0; j < 4; ++j)
                KbL[cpb2 * 64 + tx + 16 * j][ty + 16 * i] = accK[cpb2][i][j] * INV_S;
    __syncthreads();

    // ---- stage 2: P = Kb @ theta_w ----
    float (*Bt)[68] = (float (*)[68])(ldsf + 128 * 68);     // theta tile [64][68]
    float acc[4][4] = {};
    for (int kc2 = 0; kc2 < 2; ++kc2) {
        #pragma unroll
        for (int r = 0; r < 4; ++r) {
            int idx = tid + 256 * r;
            int row = idx >> 4, c4 = idx & 15;
            *(float4*)(&Bt[row][c4 * 4]) =
                *(const float4*)(theta_w + (size_t)(kc2 * 64 + row) * CC + cib + c4 * 4);
        }
        __syncthreads();
        for (int k = 0; k < 64; ++k) {
            float av[4], bv[4];
            #pragma unroll
            for (int i = 0; i < 4; ++i) av[i] = KbL[kc2 * 64 + k][ty + 16 * i];
            #pragma unroll
            for (int j = 0; j < 4; ++j) bv[j] = Bt[k][tx + 16 * j];
            #pragma unroll
            for (int i = 0; i < 4; ++i)
                #pragma unroll
                for (int j = 0; j < 4; ++j) acc[i][j] += av[i] * bv[j];
        }
        __syncthreads();
    }
    #pragma unroll
    for (int i = 0; i < 4; ++i)
        #pragma unroll
        for (int j = 0; j < 4; ++j)
            P[((size_t)b * CC + cob + ty + 16 * i) * CC + cib + tx + 16 * j] =
                __float2bfloat16(acc[i][j]);

    // ---- q from the LDS Kb tile (one ci-block-column only; no barriers below) ----
    if ((rest & 3) == 0 && tid < 64) {
        float s = w_b[cob + tid];
        #pragma unroll 8
        for (int c = 0; c < ICH; ++c) s += KbL[c][tid] * theta_b[c];
        q[b * CC + cob + tid] = s;
    }
}

// ---------------------------------------------------------------------------
// k4: m97-style MFMA  wy = P @ xt^T + q.  NO atomics: BN partial sums go to
// pbuf[c][b*32+tile] via LDS staging.  Out staging padded to stride 132.
// flat grid 512: id = b + 8*(m + 2*t) -> XCD = b (P[b] from kpq and xt[b]
// L2-hot; wy[b] stays for k6).  block 256.
// ---------------------------------------------------------------------------
__global__ __launch_bounds__(256) void k4_mfma(
    const __hip_bfloat16* __restrict__ P, const __hip_bfloat16* __restrict__ xt,
    const float* __restrict__ q, __hip_bfloat16* __restrict__ wy,
    float* __restrict__ pbuf)     // [2][256][256]: s1 then s2
{
    __shared__ short lds[128 * 132];
    __shared__ float pst1[4 * 64], pst2[4 * 64];
    short* As = lds;
    short* Bs = lds + 128 * 64;

    const int id = blockIdx.x;
    const int b  = id & 7;                           // XCD = b
    const int m0 = ((id >> 3) & 1) * 128;
    const int tt = id >> 4;                          // 0..31
    const int t0 = tt * 128;
    const int tid = threadIdx.x;
    const int w = tid >> 6, l = tid & 63;
    const int quad = l >> 4, lm = l & 15;
    const int wm = (w & 1) * 64, wn = (w >> 1) * 64;
    const int rs = l >> 3, cs = (l & 7) * 8;

    const __hip_bfloat16* Ap = P + ((size_t)b * CC + m0) * CC;
    const __hip_bfloat16* Bp = xt + ((size_t)b * TT + t0) * CC;

    floatx4 acc[4][4];
    #pragma unroll
    for (int i = 0; i < 4; ++i)
        #pragma unroll
        for (int j = 0; j < 4; ++j) acc[i][j] = (floatx4)0.f;

    for (int kc = 0; kc < 4; ++kc) {
        const int k0 = kc * 64;
        const int rbase = w * 32;
        #pragma unroll
        for (int t = 0; t < 4; ++t) {
            gl_lds16(Ap + (size_t)(rbase + t * 8 + rs) * CC + k0 + cs, &As[(rbase + t * 8) * 64]);
            gl_lds16(Bp + (size_t)(rbase + t * 8 + rs) * CC + k0 + cs, &Bs[(rbase + t * 8) * 64]);
        }
        __syncthreads();
        #pragma unroll
        for (int ks = 0; ks < 2; ++ks) {
            short8 a[4], bb[4];
            #pragma unroll
            for (int i = 0; i < 4; ++i)
                a[i] = *(const short8*)&As[(wm + i * 16 + lm) * 64 + ks * 32 + quad * 8];
            #pragma unroll
            for (int j = 0; j < 4; ++j)
                bb[j] = *(const short8*)&Bs[(wn + j * 16 + lm) * 64 + ks * 32 + quad * 8];
            #pragma unroll
            for (int i = 0; i < 4; ++i)
                #pragma unroll
                for (int j = 0; j < 4; ++j)
                    acc[i][j] = __builtin_amdgcn_mfma_f32_16x16x32_bf16(a[i], bb[j], acc[i][j], 0, 0, 0);
        }
        __syncthreads();
    }

    // epilogue A: per-wave BN partial sums -> LDS pst (no atomics)
    #pragma unroll
    for (int i = 0; i < 4; ++i) {
        #pragma unroll
        for (int r = 0; r < 4; ++r) {
            int m = wm + i * 16 + quad * 4 + r;
            float bias = q[b * CC + m0 + m];
            float s1 = 0.f, s2 = 0.f;
            #pragma unroll
            for (int j = 0; j < 4; ++j) {
                float v = acc[i][j][r] + bias;
                s1 += v; s2 += v * v;
            }
            #pragma unroll
            for (int off = 1; off < 16; off <<= 1) {
                s1 += __shfl_xor(s1, off);
                s2 += __shfl_xor(s2, off);
            }
            if (lm == 0) {
                pst1[w * 64 + i * 16 + quad * 4 + r] = s1;
                pst2[w * 64 + i * 16 + quad * 4 + r] = s2;
            }
        }
    }

    // epilogue B: +q bias, LDS-stage bf16 tile (stride 132), wide stores
    __hip_bfloat16* Out = (__hip_bfloat16*)lds;
    #pragma unroll
    for (int i = 0; i < 4; ++i) {
        #pragma unroll
        for (int r = 0; r < 4; ++r) {
            int m = wm + i * 16 + quad * 4 + r;
            float bias = q[b * CC + m0 + m];
            #pragma unroll
            for (int j = 0; j < 4; ++j)
                Out[m * 132 + wn + j * 16 + lm] = __float2bfloat16(acc[i][j][r] + bias);
        }
    }
    __syncthreads();

    // combine the two n-half waves' partials, write pbuf (128 ch per block)
    if (tid < 128) {
        int half = tid >> 6, k = tid & 63;
        float s1 = pst1[half * 64 + k] + pst1[(2 + half) * 64 + k];
        float s2 = pst2[half * 64 + k] + pst2[(2 + half) * 64 + k];
        size_t col = (size_t)b * 32 + tt;
        pbuf[(size_t)(m0 + tid) * 256 + col] = s1;
        pbuf[65536 + (size_t)(m0 + tid) * 256 + col] = s2;
    }

    #pragma unroll
    for (int it = 0; it < 8; ++it) {
        int idx = tid + 256 * it;
        int row = idx >> 4, cg = idx & 15;
        *(short8*)(wy + ((size_t)b * CC + m0 + row) * TT + t0 + cg * 8) =
            *(const short8*)&Out[row * 132 + cg * 8];
    }
}

// ---------------------------------------------------------------------------
// k6: fused BN-reduce + apply + residual.  Each block derives BN coefficients
// for its 64 channels from pbuf (L2-hot), then processes a 64ch x 256t range.
// flat grid 512: id = b + 8*(c + 4*t) -> XCD = b (wy[b], xt[b] L2-hot from
// k4/k0x).  block 256.
// ---------------------------------------------------------------------------
__global__ __launch_bounds__(256) void k6_out(
    const __hip_bfloat16* __restrict__ wy, const __hip_bfloat16* __restrict__ xt,
    const float* __restrict__ pbuf, const float* __restrict__ gamma,
    const float* __restrict__ beta, float* __restrict__ out)
{
    __shared__ float Fs[64][68];
    __shared__ float cA[64], cB[64];
    const int id = blockIdx.x;
    const int b  = id & 7;                           // XCD = b
    const int cb = ((id >> 3) & 3) * 64;
    const int tb0 = (id >> 5) * 256;
    const int tid = threadIdx.x;

    // BN coefficients: 4 lanes per channel, each sums 64 of the 256 partials
    {
        const int ch = tid >> 2, qtr = tid & 3;
        const float* p1 = pbuf + (size_t)(cb + ch) * 256 + qtr * 64;
        const float* p2 = p1 + 65536;
        float s1 = 0.f, s2 = 0.f;
        #pragma unroll
        for (int e = 0; e < 16; ++e) {
            float4 a = *(const float4*)(p1 + e * 4);
            float4 c = *(const float4*)(p2 + e * 4);
            s1 += a.x + a.y + a.z + a.w;
            s2 += c.x + c.y + c.z + c.w;
        }
        s1 += __shfl_xor(s1, 1); s1 += __shfl_xor(s1, 2);
        s2 += __shfl_xor(s2, 1); s2 += __shfl_xor(s2, 2);
        if (qtr == 0) {
            float mean = s1 * INV_BT;
            float var  = s2 * INV_BT - mean * mean;
            float A = gamma[cb + ch] * rsqrtf(var + BN_EPS);
            cA[ch] = A;
            cB[ch] = beta[cb + ch] - mean * A;
        }
    }

    for (int tt = 0; tt < 4; ++tt) {
        const int tb = tb0 + tt * 64;
        __syncthreads();   // cA/cB ready (tt==0); prior Fs consumers done (tt>0)
        {
            const int t = tid >> 2, cseg = (tid & 3) * 16;
            const __hip_bfloat16* src = xt + ((size_t)b * TT + tb + t) * CC + cb + cseg;
            short8 v0 = *(const short8*)src;
            short8 v1 = *(const short8*)(src + 8);
            const __hip_bfloat16* p0 = (const __hip_bfloat16*)&v0;
            const __hip_bfloat16* p1 = (const __hip_bfloat16*)&v1;
            #pragma unroll
            for (int e = 0; e < 8; ++e) Fs[t][cseg + e] = __bfloat162float(p0[e]);
            #pragma unroll
            for (int e = 0; e < 8; ++e) Fs[t][cseg + 8 + e] = __bfloat162float(p1[e]);
        }
        __syncthreads();
        {
            const int c = tid >> 2, seg = (tid & 3) * 16;
            const float A = cA[c], Bc = cB[c];
            const __hip_bfloat16* wsrc = wy + ((size_t)b * CC + cb + c) * TT + tb + seg;
            short8 w0 = *(const short8*)wsrc;
            short8 w1 = *(const short8*)(wsrc + 8);
            const __hip_bfloat16* q0 = (const __hip_bfloat16*)&w0;
            const __hip_bfloat16* q1 = (const __hip_bfloat16*)&w1;
            float* dst = out + ((size_t)b * CC + cb + c) * TT + tb + seg;
            #pragma unroll
            for (int e = 0; e < 8; ++e)
                dst[e] = __bfloat162float(q0[e]) * A + Bc + Fs[seg + e][c];
            #pragma unroll
            for (int e = 0; e < 8; ++e)
                dst[8 + e] = __bfloat162float(q1[e]) * A + Bc + Fs[seg + 8 + e][c];
        }
    }
}

extern "C" void kernel_launch(void* const* d_in, const int* in_sizes, int n_in,
                              void* d_out, int out_size, void* d_ws, size_t ws_size,
                              hipStream_t stream)
{
    const float* x        = (const float*)d_in[0];
    const float* theta_w  = (const float*)d_in[1];
    const float* theta_b  = (const float*)d_in[2];
    const float* phi_w    = (const float*)d_in[3];
    const float* phi_b    = (const float*)d_in[4];
    const float* g_w      = (const float*)d_in[5];
    const float* g_b      = (const float*)d_in[6];
    const float* w_w      = (const float*)d_in[7];
    const float* w_b      = (const float*)d_in[8];
    const float* bn_gamma = (const float*)d_in[9];
    const float* bn_beta  = (const float*)d_in[10];
    float* out = (float*)d_out;

    char* p = (char*)d_ws;
    __hip_bfloat16* xt    = (__hip_bfloat16*)p; p += (size_t)8388608 * 2;   // [8][4096][256]
    __hip_bfloat16* Wf    = (__hip_bfloat16*)p; p += (size_t)65536 * 2;     // [256][256]
    __hip_bfloat16* phi_g = (__hip_bfloat16*)p; p += (size_t)4194304 * 2;   // [8][256][2048]
    __hip_bfloat16* P     = (__hip_bfloat16*)p; p += (size_t)524288 * 2;    // [8][256][256]
    float* Mpart = (float*)p; p += (size_t)1048576 * 4;                     // [8][8][128][128]
    float* q     = (float*)p; p += (size_t)2048 * 4;                        // [8][256]
    __hip_bfloat16* wy = (__hip_bfloat16*)p; p += (size_t)8388608 * 2;      // [8][256][4096]
    float* pbuf  = (float*)p;                                               // [2][256][256]

    k0x_transpose<<<dim3(2112), 256, 0, stream>>>(x, xt, phi_w, g_w, Wf);
    k1_mfma<<<dim3(512), 256, 0, stream>>>(Wf, phi_b, g_b, xt, phi_g);
    k2_mfma<<<dim3(8, 8), 256, 0, stream>>>(phi_g, Mpart);
    kpq<<<dim3(128), 256, 0, stream>>>(w_w, Mpart, theta_w, theta_b, w_b, P, q);
    k4_mfma<<<dim3(512), 256, 0, stream>>>(P, xt, q, wy, pbuf);
    k6_out<<<dim3(512), 256, 0, stream>>>(wy, xt, pbuf, bn_gamma, bn_beta, out);
}

// Round 5
// 183.560 us; speedup vs baseline: 1.0255x; 1.0255x over previous
//
#include <hip/hip_runtime.h>
#include <hip/hip_bf16.h>

typedef __attribute__((ext_vector_type(8))) short short8;
typedef __attribute__((ext_vector_type(4))) short short4v;
typedef __attribute__((ext_vector_type(4))) float floatx4;
typedef unsigned int u32;

#define BB 8
#define CC 256
#define ICH 128
#define TT 4096
#define SS 2048
static constexpr float BN_EPS = 1e-5f;
static constexpr float INV_S  = 1.0f / 2048.0f;
static constexpr float INV_BT = 1.0f / 32768.0f;   // 1/(B*T)

// async global->LDS DMA, 16 B per lane; LDS dest = wave-uniform base + lane*16
typedef const __attribute__((address_space(1))) u32* gas_ptr;
typedef __attribute__((address_space(3))) u32* las_ptr;
__device__ __forceinline__ void gl_lds16(const void* g, void* l) {
    __builtin_amdgcn_global_load_lds((gas_ptr)g, (las_ptr)l, 16, 0, 0);
}

// ---------------------------------------------------------------------------
// XCD ownership model (validated rounds 2-4): XCD = blockIdx.x % 8.
// Batch b pinned to XCD b end-to-end; per-batch intermediates stay in that
// XCD's 4MB L2 (kpq round-4 FETCH 16.8->3.15 MB confirms).
// ---------------------------------------------------------------------------

// ---------------------------------------------------------------------------
// k0x: transpose + convert  x[b][c][t] (f32) -> xt[b][t][c] (bf16).
// flat grid 2112: id<2048 -> b=id&7 (XCD-pinned), ids 2048..2111 convert
// phi_w|g_w -> bf16 Wf.  block 256
// ---------------------------------------------------------------------------
__global__ __launch_bounds__(256) void k0x_transpose(
    const float* __restrict__ x, __hip_bfloat16* __restrict__ xt,
    const float* __restrict__ phi_w, const float* __restrict__ g_w,
    __hip_bfloat16* __restrict__ Wf)
{
    const int id = blockIdx.x;
    if (id >= 2048) {                      // fused weight conversion (64 blocks)
        int idx = (id - 2048) * 256 + threadIdx.x;   // 0..16383, 4 floats each
        const float* src = (idx < 8192) ? (phi_w + (size_t)idx * 4)
                                        : (g_w + (size_t)(idx - 8192) * 4);
        float4 v = *(const float4*)src;
        alignas(8) __hip_bfloat16 t[4];
        t[0] = __float2bfloat16(v.x); t[1] = __float2bfloat16(v.y);
        t[2] = __float2bfloat16(v.z); t[3] = __float2bfloat16(v.w);
        *(short4v*)(Wf + (size_t)idx * 4) = *(const short4v*)t;
        return;
    }

    __shared__ float Tl[64][65];
    const int b = id & 7, rest = id >> 3;            // XCD = b
    const int cb = (rest & 3) * 64, tb = (rest >> 2) * 64;
    const int tid = threadIdx.x;
    #pragma unroll
    for (int it = 0; it < 4; ++it) {
        int idx = tid + 256 * it;
        int row = idx >> 4, c4 = idx & 15;
        float4 v = *(const float4*)(x + ((size_t)b * CC + cb + row) * TT + tb + c4 * 4);
        Tl[row][c4 * 4 + 0] = v.x; Tl[row][c4 * 4 + 1] = v.y;
        Tl[row][c4 * 4 + 2] = v.z; Tl[row][c4 * 4 + 3] = v.w;
    }
    __syncthreads();
    #pragma unroll
    for (int it = 0; it < 2; ++it) {
        int idx = tid + 256 * it;
        int trow = idx >> 3, ch = idx & 7;
        alignas(16) __hip_bfloat16 tmp[8];
        #pragma unroll
        for (int e = 0; e < 8; ++e) tmp[e] = __float2bfloat16(Tl[ch * 8 + e][trow]);
        *(short8*)(xt + ((size_t)b * TT + tb + trow) * CC + cb + ch * 8) = *(const short8*)tmp;
    }
}

// ---------------------------------------------------------------------------
// k1: m97-style MFMA conv1x1 (stacked phi|g) + maxpool2 epilogue.
// flat grid 512: id = b + 8*(m + 2*t) -> XCD = b; xt[b] L2-hot from k0x.
// ---------------------------------------------------------------------------
__global__ __launch_bounds__(256) void k1_mfma(
    const __hip_bfloat16* __restrict__ Wf, const float* __restrict__ phi_b,
    const float* __restrict__ g_b, const __hip_bfloat16* __restrict__ xt,
    __hip_bfloat16* __restrict__ phi_g)
{
    __shared__ short lds[128 * 132];      // staging (32 KB) / Out (33 KB), reused
    short* As = lds;
    short* Bs = lds + 128 * 64;

    const int id = blockIdx.x;
    const int b  = id & 7;                           // XCD = b
    const int m0 = ((id >> 3) & 1) * 128;
    const int tb = (id >> 4) * 128;       // pre-pool t base
    const int s0 = (id >> 4) * 64;        // pooled output base
    const int tid = threadIdx.x;
    const int w = tid >> 6, l = tid & 63;
    const int quad = l >> 4, lm = l & 15;
    const int wm = (w & 1) * 64, wn = (w >> 1) * 64;
    const int rs = l >> 3, cs = (l & 7) * 8;   // staging row-sub / col

    const __hip_bfloat16* Ap = Wf + (size_t)m0 * CC;
    const __hip_bfloat16* Bp = xt + ((size_t)b * TT + tb) * CC;

    floatx4 acc[4][4];
    #pragma unroll
    for (int i = 0; i < 4; ++i)
        #pragma unroll
        for (int j = 0; j < 4; ++j) acc[i][j] = (floatx4)0.f;

    for (int kc = 0; kc < 4; ++kc) {
        const int k0 = kc * 64;
        const int rbase = w * 32;
        #pragma unroll
        for (int t = 0; t < 4; ++t) {
            gl_lds16(Ap + (size_t)(rbase + t * 8 + rs) * CC + k0 + cs, &As[(rbase + t * 8) * 64]);
            gl_lds16(Bp + (size_t)(rbase + t * 8 + rs) * CC + k0 + cs, &Bs[(rbase + t * 8) * 64]);
        }
        __syncthreads();
        #pragma unroll
        for (int ks = 0; ks < 2; ++ks) {
            short8 a[4], bb[4];
            #pragma unroll
            for (int i = 0; i < 4; ++i)
                a[i] = *(const short8*)&As[(wm + i * 16 + lm) * 64 + ks * 32 + quad * 8];
            #pragma unroll
            for (int j = 0; j < 4; ++j)
                bb[j] = *(const short8*)&Bs[(wn + j * 16 + lm) * 64 + ks * 32 + quad * 8];
            #pragma unroll
            for (int i = 0; i < 4; ++i)
                #pragma unroll
                for (int j = 0; j < 4; ++j)
                    acc[i][j] = __builtin_amdgcn_mfma_f32_16x16x32_bf16(a[i], bb[j], acc[i][j], 0, 0, 0);
        }
        __syncthreads();
    }

    // epilogue: stage pre-pool bf16 tile (stride 132), then pool + bias, wide stores
    __hip_bfloat16* Out = (__hip_bfloat16*)lds;
    #pragma unroll
    for (int i = 0; i < 4; ++i)
        #pragma unroll
        for (int j = 0; j < 4; ++j)
            #pragma unroll
            for (int r = 0; r < 4; ++r)
                Out[(wm + i * 16 + quad * 4 + r) * 132 + wn + j * 16 + lm] =
                    __float2bfloat16(acc[i][j][r]);
    __syncthreads();
    #pragma unroll
    for (int it = 0; it < 4; ++it) {
        int idx = tid + 256 * it;
        int orow = idx >> 3, grp = idx & 7;
        int o = m0 + orow;
        float bias = (o < ICH) ? phi_b[o] : g_b[o - ICH];
        short8 v0 = *(const short8*)&Out[orow * 132 + grp * 16];
        short8 v1 = *(const short8*)&Out[orow * 132 + grp * 16 + 8];
        const __hip_bfloat16* p0 = (const __hip_bfloat16*)&v0;
        const __hip_bfloat16* p1 = (const __hip_bfloat16*)&v1;
        alignas(16) __hip_bfloat16 o8[8];
        #pragma unroll
        for (int e = 0; e < 4; ++e)
            o8[e] = __float2bfloat16(
                fmaxf(__bfloat162float(p0[2 * e]), __bfloat162float(p0[2 * e + 1])) + bias);
        #pragma unroll
        for (int e = 0; e < 4; ++e)
            o8[4 + e] = __float2bfloat16(
                fmaxf(__bfloat162float(p1[2 * e]), __bfloat162float(p1[2 * e + 1])) + bias);
        *(short8*)(phi_g + ((size_t)b * CC + o) * SS + s0 + grp * 8) = *(const short8*)o8;
    }
}

// ---------------------------------------------------------------------------
// k2: MFMA Gram partials over 256-wide s-chunks.  A/B SWAPPED vs earlier
// rounds: A = g rows, B = phi rows, so the output is the transposed Gram
//   Mpart[b][sc][c][c'] = sum_s g[c][s] * phi[c'][s]
// (same values, row-major in c' -- the layout kpq's float4 reads need).
// grid (8 b, 8 sc), b on the FAST axis -> XCD = b.  block 256.
// ---------------------------------------------------------------------------
__global__ __launch_bounds__(256) void k2_mfma(
    const __hip_bfloat16* __restrict__ phi_g, float* __restrict__ Mpart)
{
    __shared__ short lds[2 * 128 * 64];
    short* As = lds;
    short* Bs = lds + 128 * 64;
    const int b = blockIdx.x, sc = blockIdx.y;     // b fast -> XCD = b
    const int tid = threadIdx.x;
    const int w = tid >> 6, l = tid & 63;
    const int quad = l >> 4, lm = l & 15;
    const int wm = (w & 1) * 64, wn = (w >> 1) * 64;
    const int rs = l >> 3, cs = (l & 7) * 8;

    const __hip_bfloat16* Ap = phi_g + (size_t)b * CC * SS + (size_t)ICH * SS + sc * 256; // g rows
    const __hip_bfloat16* Bp = phi_g + (size_t)b * CC * SS + sc * 256;                    // phi rows

    floatx4 acc[4][4];
    #pragma unroll
    for (int i = 0; i < 4; ++i)
        #pragma unroll
        for (int j = 0; j < 4; ++j) acc[i][j] = (floatx4)0.f;

    for (int kc = 0; kc < 4; ++kc) {
        const int k0 = kc * 64;
        const int rbase = w * 32;
        #pragma unroll
        for (int t = 0; t < 4; ++t) {
            gl_lds16(Ap + (size_t)(rbase + t * 8 + rs) * SS + k0 + cs, &As[(rbase + t * 8) * 64]);
            gl_lds16(Bp + (size_t)(rbase + t * 8 + rs) * SS + k0 + cs, &Bs[(rbase + t * 8) * 64]);
        }
        __syncthreads();
        #pragma unroll
        for (int ks = 0; ks < 2; ++ks) {
            short8 a[4], bb[4];
            #pragma unroll
            for (int i = 0; i < 4; ++i)
                a[i] = *(const short8*)&As[(wm + i * 16 + lm) * 64 + ks * 32 + quad * 8];
            #pragma unroll
            for (int j = 0; j < 4; ++j)
                bb[j] = *(const short8*)&Bs[(wn + j * 16 + lm) * 64 + ks * 32 + quad * 8];
            #pragma unroll
            for (int i = 0; i < 4; ++i)
                #pragma unroll
                for (int j = 0; j < 4; ++j)
                    acc[i][j] = __builtin_amdgcn_mfma_f32_16x16x32_bf16(a[i], bb[j], acc[i][j], 0, 0, 0);
        }
        __syncthreads();
    }

    float* dst = Mpart + ((size_t)(b * 8 + sc)) * ICH * ICH;   // [c][c'] layout
    #pragma unroll
    for (int i = 0; i < 4; ++i)
        #pragma unroll
        for (int j = 0; j < 4; ++j)
            #pragma unroll
            for (int r = 0; r < 4; ++r)
                dst[(size_t)(wm + i * 16 + quad * 4 + r) * ICH + wn + j * 16 + lm] = acc[i][j][r];
}

// ---------------------------------------------------------------------------
// kpq: fused k3a+k3b, LDS-b128 restructure (round-4 was ds_read_b32-bound:
// 43us at 8% VALU).  Per block: presum Mpart[b] -> Ms[c][c'] in LDS (f32),
// stage w_w^T -> Al[k][co], then
//   stage1: Kb[co][c'] = sum_k w_w[co][k]*Ms[k][c']   (av/bv = ds_read_b128)
//   stage2: P[co][ci]  = sum_k Kb[k][co]*theta[k][ci] (theta read from L2)
// All f32, FMA order per element identical to round 4 -> bit-identical out.
// 1-D grid of 128, b = bid & 7 (XCD-pinned to Mpart[b]).
// ---------------------------------------------------------------------------
__global__ __launch_bounds__(256) void kpq(
    const float* __restrict__ w_w, const float* __restrict__ Mpart,
    const float* __restrict__ theta_w, const float* __restrict__ theta_b,
    const float* __restrict__ w_b, __hip_bfloat16* __restrict__ P,
    float* __restrict__ q)
{
    __shared__ float Ms[128][128];        // summed Gram, [c][c']  (64 KB)
    __shared__ float Al[128][68];         // stage1: w_w^T[k][co]; stage2: KbL[c'][co]
    const int bid = blockIdx.x;
    const int b    = bid & 7;              // XCD-pinned to Mpart[b]'s producer
    const int rest = bid >> 3;             // 0..15
    const int cob  = (rest >> 2) * 64;
    const int cib  = (rest & 3) * 64;
    const int tid = threadIdx.x;
    const int tx = tid & 15, ty = tid >> 4;

    // ---- presum 8 partials -> Ms (float4 streaming, L2-hot) ----
    {
        const float* src = Mpart + (size_t)b * 8 * ICH * ICH;
        #pragma unroll
        for (int e = 0; e < 16; ++e) {
            int f = e * 256 + tid;                    // float4 index 0..4095
            float4 s = *(const float4*)(src + (size_t)f * 4);
            #pragma unroll
            for (int sc = 1; sc < 8; ++sc) {
                float4 m = *(const float4*)(src + (size_t)sc * ICH * ICH + (size_t)f * 4);
                s.x += m.x; s.y += m.y; s.z += m.z; s.w += m.w;
            }
            *(float4*)&Ms[f >> 5][(f & 31) * 4] = s;
        }
    }
    // ---- stage w_w^T: Al[k][co]  (row varies per lane -> conflict-free) ----
    #pragma unroll
    for (int it = 0; it < 8; ++it) {
        int idx = tid + 256 * it;                     // 0..2047
        int row = idx & 63, c4 = idx >> 6;            // c4 0..31
        float4 v = *(const float4*)(w_w + (size_t)(cob + row) * ICH + c4 * 4);
        Al[c4 * 4 + 0][row] = v.x; Al[c4 * 4 + 1][row] = v.y;
        Al[c4 * 4 + 2][row] = v.z; Al[c4 * 4 + 3][row] = v.w;
    }
    __syncthreads();

    // ---- stage 1: Kb tile in registers, b128 LDS reads ----
    // acc[i][jj]: co = cob + ty*4 + i ; c' = (jj>>2)*64 + tx*4 + (jj&3)
    float accK[4][8] = {};
    #pragma unroll 4
    for (int k = 0; k < 128; ++k) {
        float4 av = *(const float4*)&Al[k][ty * 4];
        float4 b0 = *(const float4*)&Ms[k][tx * 4];
        float4 b1 = *(const float4*)&Ms[k][64 + tx * 4];
        const float* avp = (const float*)&av;
        const float* b0p = (const float*)&b0;
        const float* b1p = (const float*)&b1;
        #pragma unroll
        for (int i = 0; i < 4; ++i) {
            #pragma unroll
            for (int j = 0; j < 4; ++j) {
                accK[i][j]     += avp[i] * b0p[j];
                accK[i][4 + j] += avp[i] * b1p[j];
            }
        }
    }
    __syncthreads();                                  // Al dead, safe to overwrite

    // ---- publish Kb -> KbL[c'][co] (aliases Al) ----
    float (*KbL)[68] = Al;
    #pragma unroll
    for (int i = 0; i < 4; ++i)
        #pragma unroll
        for (int jj = 0; jj < 8; ++jj)
            KbL[(jj >> 2) * 64 + tx * 4 + (jj & 3)][ty * 4 + i] = accK[i][jj] * INV_S;
    __syncthreads();

    // ---- stage 2: P = Kb @ theta_w ; theta read straight from L2 ----
    float acc[4][4] = {};
    #pragma unroll 8
    for (int k = 0; k < 128; ++k) {
        float4 av = *(const float4*)&KbL[k][ty * 4];
        float4 bv = *(const float4*)(theta_w + (size_t)k * CC + cib + tx * 4);
        const float* avp = (const float*)&av;
        const float* bvp = (const float*)&bv;
        #pragma unroll
        for (int i = 0; i < 4; ++i)
            #pragma unroll
            for (int j = 0; j < 4; ++j)
                acc[i][j] += avp[i] * bvp[j];
    }
    #pragma unroll
    for (int i = 0; i < 4; ++i) {
        alignas(8) __hip_bfloat16 o4[4];
        #pragma unroll
        for (int j = 0; j < 4; ++j) o4[j] = __float2bfloat16(acc[i][j]);
        *(short4v*)(P + ((size_t)b * CC + cob + ty * 4 + i) * CC + cib + tx * 4) =
            *(const short4v*)o4;
    }

    // ---- q from KbL (one ci-block-column only) ----
    if ((rest & 3) == 0 && tid < 64) {
        float s = w_b[cob + tid];
        #pragma unroll 8
        for (int c = 0; c < ICH; ++c) s += KbL[c][tid] * theta_b[c];
        q[b * CC + cob + tid] = s;
    }
}

// ---------------------------------------------------------------------------
// k4: m97-style MFMA  wy = P @ xt^T + q.  NO atomics: BN partial sums go to
// pbuf[c][b*32+tile] via LDS staging.  flat grid 512: id = b + 8*(m + 2*t).
// ---------------------------------------------------------------------------
__global__ __launch_bounds__(256) void k4_mfma(
    const __hip_bfloat16* __restrict__ P, const __hip_bfloat16* __restrict__ xt,
    const float* __restrict__ q, __hip_bfloat16* __restrict__ wy,
    float* __restrict__ pbuf)     // [2][256][256]: s1 then s2
{
    __shared__ short lds[128 * 132];
    __shared__ float pst1[4 * 64], pst2[4 * 64];
    short* As = lds;
    short* Bs = lds + 128 * 64;

    const int id = blockIdx.x;
    const int b  = id & 7;                           // XCD = b
    const int m0 = ((id >> 3) & 1) * 128;
    const int tt = id >> 4;                          // 0..31
    const int t0 = tt * 128;
    const int tid = threadIdx.x;
    const int w = tid >> 6, l = tid & 63;
    const int quad = l >> 4, lm = l & 15;
    const int wm = (w & 1) * 64, wn = (w >> 1) * 64;
    const int rs = l >> 3, cs = (l & 7) * 8;

    const __hip_bfloat16* Ap = P + ((size_t)b * CC + m0) * CC;
    const __hip_bfloat16* Bp = xt + ((size_t)b * TT + t0) * CC;

    floatx4 acc[4][4];
    #pragma unroll
    for (int i = 0; i < 4; ++i)
        #pragma unroll
        for (int j = 0; j < 4; ++j) acc[i][j] = (floatx4)0.f;

    for (int kc = 0; kc < 4; ++kc) {
        const int k0 = kc * 64;
        const int rbase = w * 32;
        #pragma unroll
        for (int t = 0; t < 4; ++t) {
            gl_lds16(Ap + (size_t)(rbase + t * 8 + rs) * CC + k0 + cs, &As[(rbase + t * 8) * 64]);
            gl_lds16(Bp + (size_t)(rbase + t * 8 + rs) * CC + k0 + cs, &Bs[(rbase + t * 8) * 64]);
        }
        __syncthreads();
        #pragma unroll
        for (int ks = 0; ks < 2; ++ks) {
            short8 a[4], bb[4];
            #pragma unroll
            for (int i = 0; i < 4; ++i)
                a[i] = *(const short8*)&As[(wm + i * 16 + lm) * 64 + ks * 32 + quad * 8];
            #pragma unroll
            for (int j = 0; j < 4; ++j)
                bb[j] = *(const short8*)&Bs[(wn + j * 16 + lm) * 64 + ks * 32 + quad * 8];
            #pragma unroll
            for (int i = 0; i < 4; ++i)
                #pragma unroll
                for (int j = 0; j < 4; ++j)
                    acc[i][j] = __builtin_amdgcn_mfma_f32_16x16x32_bf16(a[i], bb[j], acc[i][j], 0, 0, 0);
        }
        __syncthreads();
    }

    // epilogue A: per-wave BN partial sums -> LDS pst (no atomics)
    #pragma unroll
    for (int i = 0; i < 4; ++i) {
        #pragma unroll
        for (int r = 0; r < 4; ++r) {
            int m = wm + i * 16 + quad * 4 + r;
            float bias = q[b * CC + m0 + m];
            float s1 = 0.f, s2 = 0.f;
            #pragma unroll
            for (int j = 0; j < 4; ++j) {
                float v = acc[i][j][r] + bias;
                s1 += v; s2 += v * v;
            }
            #pragma unroll
            for (int off = 1; off < 16; off <<= 1) {
                s1 += __shfl_xor(s1, off);
                s2 += __shfl_xor(s2, off);
            }
            if (lm == 0) {
                pst1[w * 64 + i * 16 + quad * 4 + r] = s1;
                pst2[w * 64 + i * 16 + quad * 4 + r] = s2;
            }
        }
    }

    // epilogue B: +q bias, LDS-stage bf16 tile (stride 132), wide stores
    __hip_bfloat16* Out = (__hip_bfloat16*)lds;
    #pragma unroll
    for (int i = 0; i < 4; ++i) {
        #pragma unroll
        for (int r = 0; r < 4; ++r) {
            int m = wm + i * 16 + quad * 4 + r;
            float bias = q[b * CC + m0 + m];
            #pragma unroll
            for (int j = 0; j < 4; ++j)
                Out[m * 132 + wn + j * 16 + lm] = __float2bfloat16(acc[i][j][r] + bias);
        }
    }
    __syncthreads();

    // combine the two n-half waves' partials, write pbuf (128 ch per block)
    if (tid < 128) {
        int half = tid >> 6, k = tid & 63;
        float s1 = pst1[half * 64 + k] + pst1[(2 + half) * 64 + k];
        float s2 = pst2[half * 64 + k] + pst2[(2 + half) * 64 + k];
        size_t col = (size_t)b * 32 + tt;
        pbuf[(size_t)(m0 + tid) * 256 + col] = s1;
        pbuf[65536 + (size_t)(m0 + tid) * 256 + col] = s2;
    }

    #pragma unroll
    for (int it = 0; it < 8; ++it) {
        int idx = tid + 256 * it;
        int row = idx >> 4, cg = idx & 15;
        *(short8*)(wy + ((size_t)b * CC + m0 + row) * TT + t0 + cg * 8) =
            *(const short8*)&Out[row * 132 + cg * 8];
    }
}

// ---------------------------------------------------------------------------
// k6: fused BN-reduce + apply + residual.  flat grid 512: id = b + 8*(c+4*t)
// -> XCD = b (wy[b], xt[b] L2-hot).  block 256.
// ---------------------------------------------------------------------------
__global__ __launch_bounds__(256) void k6_out(
    const __hip_bfloat16* __restrict__ wy, const __hip_bfloat16* __restrict__ xt,
    const float* __restrict__ pbuf, const float* __restrict__ gamma,
    const float* __restrict__ beta, float* __restrict__ out)
{
    __shared__ float Fs[64][68];
    __shared__ float cA[64], cB[64];
    const int id = blockIdx.x;
    const int b  = id & 7;                           // XCD = b
    const int cb = ((id >> 3) & 3) * 64;
    const int tb0 = (id >> 5) * 256;
    const int tid = threadIdx.x;

    // BN coefficients: 4 lanes per channel, each sums 64 of the 256 partials
    {
        const int ch = tid >> 2, qtr = tid & 3;
        const float* p1 = pbuf + (size_t)(cb + ch) * 256 + qtr * 64;
        const float* p2 = p1 + 65536;
        float s1 = 0.f, s2 = 0.f;
        #pragma unroll
        for (int e = 0; e < 16; ++e) {
            float4 a = *(const float4*)(p1 + e * 4);
            float4 c = *(const float4*)(p2 + e * 4);
            s1 += a.x + a.y + a.z + a.w;
            s2 += c.x + c.y + c.z + c.w;
        }
        s1 += __shfl_xor(s1, 1); s1 += __shfl_xor(s1, 2);
        s2 += __shfl_xor(s2, 1); s2 += __shfl_xor(s2, 2);
        if (qtr == 0) {
            float mean = s1 * INV_BT;
            float var  = s2 * INV_BT - mean * mean;
            float A = gamma[cb + ch] * rsqrtf(var + BN_EPS);
            cA[ch] = A;
            cB[ch] = beta[cb + ch] - mean * A;
        }
    }

    for (int tt = 0; tt < 4; ++tt) {
        const int tb = tb0 + tt * 64;
        __syncthreads();   // cA/cB ready (tt==0); prior Fs consumers done (tt>0)
        {
            const int t = tid >> 2, cseg = (tid & 3) * 16;
            const __hip_bfloat16* src = xt + ((size_t)b * TT + tb + t) * CC + cb + cseg;
            short8 v0 = *(const short8*)src;
            short8 v1 = *(const short8*)(src + 8);
            const __hip_bfloat16* p0 = (const __hip_bfloat16*)&v0;
            const __hip_bfloat16* p1 = (const __hip_bfloat16*)&v1;
            #pragma unroll
            for (int e = 0; e < 8; ++e) Fs[t][cseg + e] = __bfloat162float(p0[e]);
            #pragma unroll
            for (int e = 0; e < 8; ++e) Fs[t][cseg + 8 + e] = __bfloat162float(p1[e]);
        }
        __syncthreads();
        {
            const int c = tid >> 2, seg = (tid & 3) * 16;
            const float A = cA[c], Bc = cB[c];
            const __hip_bfloat16* wsrc = wy + ((size_t)b * CC + cb + c) * TT + tb + seg;
            short8 w0 = *(const short8*)wsrc;
            short8 w1 = *(const short8*)(wsrc + 8);
            const __hip_bfloat16* q0 = (const __hip_bfloat16*)&w0;
            const __hip_bfloat16* q1 = (const __hip_bfloat16*)&w1;
            float* dst = out + ((size_t)b * CC + cb + c) * TT + tb + seg;
            #pragma unroll
            for (int e = 0; e < 8; ++e)
                dst[e] = __bfloat162float(q0[e]) * A + Bc + Fs[seg + e][c];
            #pragma unroll
            for (int e = 0; e < 8; ++e)
                dst[8 + e] = __bfloat162float(q1[e]) * A + Bc + Fs[seg + 8 + e][c];
        }
    }
}

extern "C" void kernel_launch(void* const* d_in, const int* in_sizes, int n_in,
                              void* d_out, int out_size, void* d_ws, size_t ws_size,
                              hipStream_t stream)
{
    const float* x        = (const float*)d_in[0];
    const float* theta_w  = (const float*)d_in[1];
    const float* theta_b  = (const float*)d_in[2];
    const float* phi_w    = (const float*)d_in[3];
    const float* phi_b    = (const float*)d_in[4];
    const float* g_w      = (const float*)d_in[5];
    const float* g_b      = (const float*)d_in[6];
    const float* w_w      = (const float*)d_in[7];
    const float* w_b      = (const float*)d_in[8];
    const float* bn_gamma = (const float*)d_in[9];
    const float* bn_beta  = (const float*)d_in[10];
    float* out = (float*)d_out;

    char* p = (char*)d_ws;
    __hip_bfloat16* xt    = (__hip_bfloat16*)p; p += (size_t)8388608 * 2;   // [8][4096][256]
    __hip_bfloat16* Wf    = (__hip_bfloat16*)p; p += (size_t)65536 * 2;     // [256][256]
    __hip_bfloat16* phi_g = (__hip_bfloat16*)p; p += (size_t)4194304 * 2;   // [8][256][2048]
    __hip_bfloat16* P     = (__hip_bfloat16*)p; p += (size_t)524288 * 2;    // [8][256][256]
    float* Mpart = (float*)p; p += (size_t)1048576 * 4;                     // [8][8][128][128]
    float* q     = (float*)p; p += (size_t)2048 * 4;                        // [8][256]
    __hip_bfloat16* wy = (__hip_bfloat16*)p; p += (size_t)8388608 * 2;      // [8][256][4096]
    float* pbuf  = (float*)p;                                               // [2][256][256]

    k0x_transpose<<<dim3(2112), 256, 0, stream>>>(x, xt, phi_w, g_w, Wf);
    k1_mfma<<<dim3(512), 256, 0, stream>>>(Wf, phi_b, g_b, xt, phi_g);
    k2_mfma<<<dim3(8, 8), 256, 0, stream>>>(phi_g, Mpart);
    kpq<<<dim3(128), 256, 0, stream>>>(w_w, Mpart, theta_w, theta_b, w_b, P, q);
    k4_mfma<<<dim3(512), 256, 0, stream>>>(P, xt, q, wy, pbuf);
    k6_out<<<dim3(512), 256, 0, stream>>>(wy, xt, pbuf, bn_gamma, bn_beta, out);
}